// Round 10
// baseline (480.701 us; speedup 1.0000x reference)
//
#include <hip/hip_runtime.h>
#include <cstdint>
#include <cmath>

#define DH 64
#define SQB 2048
#define SKVB 1024
#define DE 512

typedef _Float16 f16;
typedef _Float16 f16x8 __attribute__((ext_vector_type(8)));
typedef float f32x4 __attribute__((ext_vector_type(4)));
typedef float f32x16 __attribute__((ext_vector_type(16)));

#define MFMA32(A, B, C) __builtin_amdgcn_mfma_f32_32x32x16_f16(A, B, C, 0, 0, 0)

// ---------------------------------------------------------------------------
// Split fp32 -> (hi, lo) fp16 pair, optional pre-scale.
// ---------------------------------------------------------------------------
__global__ __launch_bounds__(256)
void split_f16(const float* __restrict__ in, f16* __restrict__ hi,
               f16* __restrict__ lo, int n4, float scale) {
  const int i = blockIdx.x * 256 + threadIdx.x;
  if (i >= n4) return;
  float4 v = ((const float4*)in)[i];
  v.x *= scale; v.y *= scale; v.z *= scale; v.w *= scale;
  f16 h0 = (f16)v.x, h1 = (f16)v.y, h2 = (f16)v.z, h3 = (f16)v.w;
  f16 l0 = (f16)(v.x - (float)h0), l1 = (f16)(v.y - (float)h1);
  f16 l2 = (f16)(v.z - (float)h2), l3 = (f16)(v.w - (float)h3);
  f16 hb[4] = {h0, h1, h2, h3};
  f16 lb[4] = {l0, l1, l2, l3};
  ((uint2*)hi)[i] = *(const uint2*)hb;
  ((uint2*)lo)[i] = *(const uint2*)lb;
}

// ---------------------------------------------------------------------------
// MFMA f16 GEMM (validated R4/R5 core). OUT=0: C fp32. OUT=1: split-f16 pair.
// ---------------------------------------------------------------------------
template <int NSPLIT, int OUT>
__global__ __launch_bounds__(256, 2)
void gemm_f16(const f16* __restrict__ Ah, const f16* __restrict__ Al,
              const f16* __restrict__ Wh, const f16* __restrict__ Wl,
              const float* __restrict__ bias, float* __restrict__ C,
              f16* __restrict__ Ch, f16* __restrict__ Cl,
              int M, int N, int K, float inv, float oscale) {
  __shared__ f16 smem[(NSPLIT == 3 ? 4 : 2) * 4096];
  f16* As  = smem;
  f16* Als = (NSPLIT == 3) ? smem + 4096 : nullptr;
  f16* Ws  = smem + (NSPLIT == 3 ? 8192 : 4096);
  f16* Wls = (NSPLIT == 3) ? smem + 12288 : nullptr;

  const int tid = threadIdx.x;
  const int w = tid >> 6;
  const int l = tid & 63;
  const int wm = w >> 1, wn = w & 1;
  const int m0 = blockIdx.y * 128;
  const int n0 = blockIdx.x * 128;

  const int srow = tid >> 2;
  const int schk = tid & 3;
  const f16* pA  = Ah + (size_t)(m0 + srow) * K + schk * 8;
  const f16* pW  = Wh + (size_t)(n0 + srow) * K + schk * 8;
  const f16* pAl = (NSPLIT == 3) ? Al + (size_t)(m0 + srow) * K + schk * 8 : nullptr;
  const f16* pWl = (NSPLIT == 3) ? Wl + (size_t)(n0 + srow) * K + schk * 8 : nullptr;
  const size_t rowskip = (size_t)64 * K;

  const int d0 = srow * 32 + ((schk ^ (srow & 3)) * 8);
  const int fbase = (l & 15) * 32 + (((l >> 4) ^ (l & 3)) * 8);
  const int fA = wm * 2048 + fbase;
  const int fW = wn * 2048 + fbase;

  f32x4 acc[4][4] = {};
  uint4 rA0, rA1, rW0, rW1, rAl0, rAl1, rWl0, rWl1;

  rA0 = *(const uint4*)(pA);            rA1 = *(const uint4*)(pA + rowskip);
  rW0 = *(const uint4*)(pW);            rW1 = *(const uint4*)(pW + rowskip);
  if constexpr (NSPLIT == 3) {
    rAl0 = *(const uint4*)(pAl);        rAl1 = *(const uint4*)(pAl + rowskip);
    rWl0 = *(const uint4*)(pWl);        rWl1 = *(const uint4*)(pWl + rowskip);
  }

  for (int k0 = 0; k0 < K; k0 += 32) {
    __syncthreads();
    *(uint4*)&As[d0] = rA0;  *(uint4*)&As[d0 + 2048] = rA1;
    *(uint4*)&Ws[d0] = rW0;  *(uint4*)&Ws[d0 + 2048] = rW1;
    if constexpr (NSPLIT == 3) {
      *(uint4*)&Als[d0] = rAl0;  *(uint4*)&Als[d0 + 2048] = rAl1;
      *(uint4*)&Wls[d0] = rWl0;  *(uint4*)&Wls[d0 + 2048] = rWl1;
    }
    __syncthreads();

    if (k0 + 32 < K) {
      rA0 = *(const uint4*)(pA + k0 + 32);  rA1 = *(const uint4*)(pA + rowskip + k0 + 32);
      rW0 = *(const uint4*)(pW + k0 + 32);  rW1 = *(const uint4*)(pW + rowskip + k0 + 32);
      if constexpr (NSPLIT == 3) {
        rAl0 = *(const uint4*)(pAl + k0 + 32); rAl1 = *(const uint4*)(pAl + rowskip + k0 + 32);
        rWl0 = *(const uint4*)(pWl + k0 + 32); rWl1 = *(const uint4*)(pWl + rowskip + k0 + 32);
      }
    }

    f16x8 ah[4], wh[4], al[4], wl[4];
#pragma unroll
    for (int i = 0; i < 4; ++i) ah[i] = *(const f16x8*)&As[fA + i * 512];
#pragma unroll
    for (int j = 0; j < 4; ++j) wh[j] = *(const f16x8*)&Ws[fW + j * 512];
    if constexpr (NSPLIT == 3) {
#pragma unroll
      for (int i = 0; i < 4; ++i) al[i] = *(const f16x8*)&Als[fA + i * 512];
#pragma unroll
      for (int j = 0; j < 4; ++j) wl[j] = *(const f16x8*)&Wls[fW + j * 512];
    }

#pragma unroll
    for (int i = 0; i < 4; ++i)
#pragma unroll
      for (int j = 0; j < 4; ++j)
        acc[i][j] = __builtin_amdgcn_mfma_f32_16x16x32_f16(ah[i], wh[j], acc[i][j], 0, 0, 0);
    if constexpr (NSPLIT == 3) {
#pragma unroll
      for (int i = 0; i < 4; ++i)
#pragma unroll
        for (int j = 0; j < 4; ++j)
          acc[i][j] = __builtin_amdgcn_mfma_f32_16x16x32_f16(ah[i], wl[j], acc[i][j], 0, 0, 0);
#pragma unroll
      for (int i = 0; i < 4; ++i)
#pragma unroll
        for (int j = 0; j < 4; ++j)
          acc[i][j] = __builtin_amdgcn_mfma_f32_16x16x32_f16(al[i], wh[j], acc[i][j], 0, 0, 0);
    }
  }

  const int rr = (l >> 4) * 4;
  const int cc = l & 15;
#pragma unroll
  for (int j = 0; j < 4; ++j) {
    const int n = n0 + wn * 64 + j * 16 + cc;
    const float bv = bias[n];
#pragma unroll
    for (int i = 0; i < 4; ++i) {
      const int m = m0 + wm * 64 + i * 16 + rr;
#pragma unroll
      for (int r = 0; r < 4; ++r) {
        const float val = acc[i][j][r] * inv + bv;
        if constexpr (OUT == 0) {
          C[(size_t)(m + r) * N + n] = val;
        } else {
          const float sv = val * oscale;
          const f16 hh = (f16)sv;
          const f16 ll = (f16)(sv - (float)hh);
          Ch[(size_t)(m + r) * N + n] = hh;
          Cl[(size_t)(m + r) * N + n] = ll;
        }
      }
    }
  }
}

// ---------------------------------------------------------------------------
// One 32(kv)x32(q) S-tile via split-3 MFMA (hh + lo_k*hi_q + hi_k*lo_q).
// ---------------------------------------------------------------------------
__device__ __forceinline__ f32x16 qk_tile(const f16x8 kh8[4], const f16x8 kl8[4],
                                          const f16x8 qh_[4], const f16x8 ql_[4]) {
  f32x16 ca = (f32x16){};
  f32x16 cb = (f32x16){};
  ca = MFMA32(kh8[0], qh_[0], ca);  cb = MFMA32(kh8[1], qh_[1], cb);
  ca = MFMA32(kh8[2], qh_[2], ca);  cb = MFMA32(kh8[3], qh_[3], cb);
  ca = MFMA32(kl8[0], qh_[0], ca);  cb = MFMA32(kl8[1], qh_[1], cb);
  ca = MFMA32(kl8[2], qh_[2], ca);  cb = MFMA32(kl8[3], qh_[3], cb);
  ca = MFMA32(kh8[0], ql_[0], ca);  cb = MFMA32(kh8[1], ql_[1], cb);
  ca = MFMA32(kh8[2], ql_[2], ca);  cb = MFMA32(kh8[3], ql_[3], cb);
  return ca + cb;
}

// ---------------------------------------------------------------------------
// Fused sparse attention v9: ONE WAVE per block owns 32 full q-rows.
// Loops all 32 kv-tiles (32x32x16 split-3 MFMA, v8-validated layout:
// q col = l&31, kv = t*32 + (r&3) + 8*(r>>2) + 4*(l>>5)).
// Pass 1: online m (plain fmax), Z/H vs m=0 (|s_true|<~1.5 -> safe).
// tk from entropy; tk==1 => thr=m exactly (tie count irrelevant).
// Pass 2: recompute tiles, gather (pos, p) of s>=thr into per-lane-half
// LDS lists (deterministic). General tk>1 handled by recompute extraction.
// Zero barriers across waves (single-wave blocks) -> waves drift freely.
// ---------------------------------------------------------------------------
__global__ __launch_bounds__(64)
void attn_v9(const f16* __restrict__ qhb, const f16* __restrict__ qlb,
             const f16* __restrict__ khb, const f16* __restrict__ klb,
             const float* __restrict__ vb, f16* __restrict__ ob) {
  __shared__ int   lkv[32][2][20];
  __shared__ float lpv[32][2][20];
  __shared__ int   cnts[32][2];

  const int phys = blockIdx.x;
  const int bid = (phys & 7) * 512 + (phys >> 3);   // batch -> XCD, bijective
  const int b  = bid >> 9;
  const int h  = (bid >> 6) & 7;
  const int q0 = (bid & 63) * 32;
  const int l  = threadIdx.x;
  const int q5 = l & 31;
  const int hi5 = l >> 5;

  const float C2 = 1.44269504f / 4096.0f;   // log2(e)/4096 (s_raw = 4096*s)

  // ---- Q fragments (B operand), persistent
  const f16* qbh = qhb + (size_t)(b * SQB + q0 + q5) * DE + h * DH + hi5 * 8;
  const f16* qbl = qlb + (size_t)(b * SQB + q0 + q5) * DE + h * DH + hi5 * 8;
  f16x8 qh_[4], ql_[4];
#pragma unroll
  for (int s = 0; s < 4; ++s) {
    qh_[s] = *(const f16x8*)(qbh + s * 16);
    ql_[s] = *(const f16x8*)(qbl + s * 16);
  }

  // ---- K base (A operand); tile t at +t*32*DE = +t*16384 elements
  const size_t koff = (size_t)(b * SKVB + q5) * DE + h * DH + hi5 * 8;
  const f16* kbh = khb + koff;
  const f16* kbl = klb + koff;

  // ================= pass 1: m, Z, H ==================
  float m = -INFINITY, Z = 0.f, Hs = 0.f;
  {
    const f16* kph = kbh;
    const f16* kpl = kbl;
    f16x8 ch[4], cl_[4], nh[4], nl[4];
#pragma unroll
    for (int s = 0; s < 4; ++s) {
      ch[s]  = *(const f16x8*)(kph + s * 16);
      cl_[s] = *(const f16x8*)(kpl + s * 16);
    }
#pragma unroll 4
    for (int t = 0; t < 32; ++t) {
      if (t < 31) {
#pragma unroll
        for (int s = 0; s < 4; ++s) {
          nh[s] = *(const f16x8*)(kph + 16384 + s * 16);
          nl[s] = *(const f16x8*)(kpl + 16384 + s * 16);
        }
        kph += 16384; kpl += 16384;
      }
      const f32x16 sv = qk_tile(ch, cl_, qh_, ql_);
#pragma unroll
      for (int r = 0; r < 16; ++r) {
        m = fmaxf(m, sv[r]);
        const float e = __builtin_amdgcn_exp2f(sv[r] * C2);
        Z += e;
        Hs = fmaf(e, sv[r], Hs);
      }
      if (t < 31) {
#pragma unroll
        for (int s = 0; s < 4; ++s) { ch[s] = nh[s]; cl_[s] = nl[s]; }
      }
    }
  }
  // pair combine (row q5 lives in lanes q5 and q5+32)
  m  = fmaxf(m, __shfl_xor(m, 32));
  Z  += __shfl_xor(Z, 32);
  Hs += __shfl_xor(Hs, 32);

  // entropy (m=0 reference; mathematically identical, fp-safe at |s|<2):
  // E = ln(Z0) - (H0/4096)/Z0
  const float E = __logf(Z) - (Hs * (1.0f / 4096.0f)) / Z;
  int tk = (int)(32.0f * (1.0f - E));
  tk = tk < 1 ? 1 : (tk > 32 ? 32 : tk);

  float thr = m;   // exact for tk==1 (all ties selected, matching reference)

  // ---- general path (tk>1): recompute-based duplicate-aware extraction
  if (__ballot(tk > 1) != 0ull) {
    bool pend = (tk > 1);
    float rem = (float)tk, cand = m;
    int guard = 0;
    while (__ballot(pend) != 0ull && guard < 40) {
      ++guard;
      float cf = 0.f, nmax = -INFINITY;
      const f16* rkh = kbh;
      const f16* rkl = kbl;
      for (int t = 0; t < 32; ++t) {
        f16x8 th[4], tl[4];
#pragma unroll
        for (int s = 0; s < 4; ++s) {
          th[s] = *(const f16x8*)(rkh + s * 16);
          tl[s] = *(const f16x8*)(rkl + s * 16);
        }
        rkh += 16384; rkl += 16384;
        const f32x16 sv = qk_tile(th, tl, qh_, ql_);
#pragma unroll
        for (int r = 0; r < 16; ++r) {
          cf += (sv[r] == cand) ? 1.f : 0.f;
          nmax = (sv[r] < cand) ? fmaxf(nmax, sv[r]) : nmax;
        }
      }
      cf += __shfl_xor(cf, 32);
      nmax = fmaxf(nmax, __shfl_xor(nmax, 32));
      if (pend) {
        if (cf >= rem) { thr = cand; pend = false; }
        else { rem -= cf; cand = nmax; }
      }
    }
  }

  // ================= pass 2: gather selected (pos, p) ==================
  int myc = 0;
  {
    const f16* kph = kbh;
    const f16* kpl = kbl;
#pragma unroll 4
    for (int t = 0; t < 32; ++t) {
      f16x8 th[4], tl[4];
#pragma unroll
      for (int s = 0; s < 4; ++s) {
        th[s] = *(const f16x8*)(kph + s * 16);
        tl[s] = *(const f16x8*)(kpl + s * 16);
      }
      kph += 16384; kpl += 16384;
      const f32x16 sv = qk_tile(th, tl, qh_, ql_);
#pragma unroll
      for (int r = 0; r < 16; ++r) {
        if (sv[r] >= thr) {
          if (myc < 20) {
            lkv[q5][hi5][myc] = t * 32 + (r & 3) + 8 * (r >> 2) + 4 * hi5;
            lpv[q5][hi5][myc] = __builtin_amdgcn_exp2f((sv[r] - m) * C2);
          }
          ++myc;
        }
      }
    }
  }
  cnts[q5][hi5] = myc;
  __syncthreads();   // single-wave: cheap; orders LDS lists before PV

  // ================= PV + renorm + output ==================
  {
    const float* vbase = vb + (size_t)(b * SKVB) * DE + h * DH + l;   // lane = d
    for (int r = 0; r < 32; ++r) {
      const float Zr = __shfl(Z, r);
      const float mr = __shfl(m, r);
      int c0 = cnts[r][0]; c0 = c0 > 20 ? 20 : c0;
      int c1 = cnts[r][1]; c1 = c1 > 20 ? 20 : c1;
      float acc = 0.f, ps = 0.f;
      for (int e = 0; e < c0; ++e) {
        const int kv = lkv[r][0][e];
        const float p = lpv[r][0][e];
        ps += p;
        acc = fmaf(p, vbase[(size_t)kv * DE], acc);
      }
      for (int e = 0; e < c1; ++e) {
        const int kv = lkv[r][1][e];
        const float p = lpv[r][1][e];
        ps += p;
        acc = fmaf(p, vbase[(size_t)kv * DE], acc);
      }
      // reference: out = sum(p*V) / (sum_sel p + 1e-8 * Z_m), Z_m = Z0*exp(-m)
      const float zeps = 1e-8f * Zr * __builtin_amdgcn_exp2f(-mr * C2);
      const float o = acc / (ps + zeps);
      ob[(size_t)(b * SQB + q0 + r) * DE + h * DH + l] = (f16)o;
    }
  }
}

// ---------------------------------------------------------------------------
extern "C" void kernel_launch(void* const* d_in, const int* in_sizes, int n_in,
                              void* d_out, int out_size, void* d_ws, size_t ws_size,
                              hipStream_t stream) {
  const float* x  = (const float*)d_in[0];
  const float* y  = (const float*)d_in[1];
  const float* wq = (const float*)d_in[2];
  const float* bq = (const float*)d_in[3];
  const float* wk = (const float*)d_in[4];
  const float* bk = (const float*)d_in[5];
  const float* wv = (const float*)d_in[6];
  const float* bv = (const float*)d_in[7];
  const float* wo = (const float*)d_in[8];
  const float* bo = (const float*)d_in[9];
  float* out = (float*)d_out;

  char* ws = (char*)d_ws;
  const size_t MiB = 1048576;

  f16* xh  = (f16*)(ws);                       // 16 MiB
  f16* xl  = (f16*)(ws + 16 * MiB);            // 16
  f16* yh  = (f16*)(ws + 32 * MiB);            // 12
  f16* yl  = (f16*)(ws + 44 * MiB);            // 12
  f16* qh  = (f16*)(ws + 56 * MiB);            // 16
  f16* ql  = (f16*)(ws + 72 * MiB);            // 16
  f16* kh  = (f16*)(ws + 88 * MiB);            // 8
  f16* kl  = (f16*)(ws + 96 * MiB);            // 8
  float* v = (float*)(ws + 104 * MiB);         // 16 (f32)
  f16* ao  = (f16*)(ws + 120 * MiB);           // 16
  f16* wqh = (f16*)(ws + 136 * MiB);
  f16* wql = (f16*)(ws + 136 * MiB + 524288);
  f16* wkh = (f16*)(ws + 137 * MiB);
  f16* wkl = (f16*)(ws + 137 * MiB + 786432);
  f16* wvh = (f16*)(ws + 138 * MiB + 524288);
  f16* wvl = (f16*)(ws + 139 * MiB + 262144);
  f16* woh = (f16*)(ws + 140 * MiB);
  f16* wol = (f16*)(ws + 140 * MiB + 524288);

  dim3 blk(256);
  const float WS = 2048.0f, IWS = 1.0f / 2048.0f;

  split_f16<<<dim3(8192), blk, 0, stream>>>(x, xh, xl, 2097152, 1.0f);
  split_f16<<<dim3(6144), blk, 0, stream>>>(y, yh, yl, 1572864, 1.0f);
  split_f16<<<dim3(256),  blk, 0, stream>>>(wq, wqh, wql, 65536, WS);
  split_f16<<<dim3(384),  blk, 0, stream>>>(wk, wkh, wkl, 98304, WS);
  split_f16<<<dim3(384),  blk, 0, stream>>>(wv, wvh, wvl, 98304, 1.0f);
  split_f16<<<dim3(256),  blk, 0, stream>>>(wo, woh, wol, 65536, 1.0f);

  // Q-proj -> split pair scaled x8  (q_true * 0.125 * 64)
  gemm_f16<3, 1><<<dim3(4, 128), blk, 0, stream>>>(xh, xl, wqh, wql, bq,
      nullptr, qh, ql, 16384, 512, 512, IWS, 8.0f);
  // K-proj -> split pair scaled x64
  gemm_f16<3, 1><<<dim3(4, 64), blk, 0, stream>>>(yh, yl, wkh, wkl, bk,
      nullptr, kh, kl, 8192, 512, 768, IWS, 64.0f);
  // V-proj -> f32
  gemm_f16<1, 0><<<dim3(4, 64), blk, 0, stream>>>(yh, nullptr, wvh, nullptr, bv,
      v, nullptr, nullptr, 8192, 512, 768, 1.0f, 1.0f);

  attn_v9<<<dim3(4096), dim3(64), 0, stream>>>(qh, ql, kh, kl, v, ao);

  // O-proj
  gemm_f16<1, 0><<<dim3(4, 128), blk, 0, stream>>>(ao, nullptr, woh, nullptr, bo,
      out, nullptr, nullptr, 16384, 512, 512, 1.0f, 1.0f);
}

// Round 11
// 255.916 us; speedup vs baseline: 1.8784x; 1.8784x over previous
//
#include <hip/hip_runtime.h>
#include <cstdint>
#include <cmath>

#define DH 64
#define SQB 2048
#define SKVB 1024
#define DE 512

typedef _Float16 f16;
typedef _Float16 f16x8 __attribute__((ext_vector_type(8)));
typedef float f32x4 __attribute__((ext_vector_type(4)));
typedef float f32x16 __attribute__((ext_vector_type(16)));

#define MFMA32(A, B, C) __builtin_amdgcn_mfma_f32_32x32x16_f16(A, B, C, 0, 0, 0)

// ---------------------------------------------------------------------------
// Split fp32 -> (hi, lo) fp16 pair, optional pre-scale.
// ---------------------------------------------------------------------------
__global__ __launch_bounds__(256)
void split_f16(const float* __restrict__ in, f16* __restrict__ hi,
               f16* __restrict__ lo, int n4, float scale) {
  const int i = blockIdx.x * 256 + threadIdx.x;
  if (i >= n4) return;
  float4 v = ((const float4*)in)[i];
  v.x *= scale; v.y *= scale; v.z *= scale; v.w *= scale;
  f16 h0 = (f16)v.x, h1 = (f16)v.y, h2 = (f16)v.z, h3 = (f16)v.w;
  f16 l0 = (f16)(v.x - (float)h0), l1 = (f16)(v.y - (float)h1);
  f16 l2 = (f16)(v.z - (float)h2), l3 = (f16)(v.w - (float)h3);
  f16 hb[4] = {h0, h1, h2, h3};
  f16 lb[4] = {l0, l1, l2, l3};
  ((uint2*)hi)[i] = *(const uint2*)hb;
  ((uint2*)lo)[i] = *(const uint2*)lb;
}

// ---------------------------------------------------------------------------
// MFMA f16 GEMM (validated R4/R5 core). OUT=0: C fp32. OUT=1: split-f16 pair.
// ---------------------------------------------------------------------------
template <int NSPLIT, int OUT>
__global__ __launch_bounds__(256, 2)
void gemm_f16(const f16* __restrict__ Ah, const f16* __restrict__ Al,
              const f16* __restrict__ Wh, const f16* __restrict__ Wl,
              const float* __restrict__ bias, float* __restrict__ C,
              f16* __restrict__ Ch, f16* __restrict__ Cl,
              int M, int N, int K, float inv, float oscale) {
  __shared__ f16 smem[(NSPLIT == 3 ? 4 : 2) * 4096];
  f16* As  = smem;
  f16* Als = (NSPLIT == 3) ? smem + 4096 : nullptr;
  f16* Ws  = smem + (NSPLIT == 3 ? 8192 : 4096);
  f16* Wls = (NSPLIT == 3) ? smem + 12288 : nullptr;

  const int tid = threadIdx.x;
  const int w = tid >> 6;
  const int l = tid & 63;
  const int wm = w >> 1, wn = w & 1;
  const int m0 = blockIdx.y * 128;
  const int n0 = blockIdx.x * 128;

  const int srow = tid >> 2;
  const int schk = tid & 3;
  const f16* pA  = Ah + (size_t)(m0 + srow) * K + schk * 8;
  const f16* pW  = Wh + (size_t)(n0 + srow) * K + schk * 8;
  const f16* pAl = (NSPLIT == 3) ? Al + (size_t)(m0 + srow) * K + schk * 8 : nullptr;
  const f16* pWl = (NSPLIT == 3) ? Wl + (size_t)(n0 + srow) * K + schk * 8 : nullptr;
  const size_t rowskip = (size_t)64 * K;

  const int d0 = srow * 32 + ((schk ^ (srow & 3)) * 8);
  const int fbase = (l & 15) * 32 + (((l >> 4) ^ (l & 3)) * 8);
  const int fA = wm * 2048 + fbase;
  const int fW = wn * 2048 + fbase;

  f32x4 acc[4][4] = {};
  uint4 rA0, rA1, rW0, rW1, rAl0, rAl1, rWl0, rWl1;

  rA0 = *(const uint4*)(pA);            rA1 = *(const uint4*)(pA + rowskip);
  rW0 = *(const uint4*)(pW);            rW1 = *(const uint4*)(pW + rowskip);
  if constexpr (NSPLIT == 3) {
    rAl0 = *(const uint4*)(pAl);        rAl1 = *(const uint4*)(pAl + rowskip);
    rWl0 = *(const uint4*)(pWl);        rWl1 = *(const uint4*)(pWl + rowskip);
  }

  for (int k0 = 0; k0 < K; k0 += 32) {
    __syncthreads();
    *(uint4*)&As[d0] = rA0;  *(uint4*)&As[d0 + 2048] = rA1;
    *(uint4*)&Ws[d0] = rW0;  *(uint4*)&Ws[d0 + 2048] = rW1;
    if constexpr (NSPLIT == 3) {
      *(uint4*)&Als[d0] = rAl0;  *(uint4*)&Als[d0 + 2048] = rAl1;
      *(uint4*)&Wls[d0] = rWl0;  *(uint4*)&Wls[d0 + 2048] = rWl1;
    }
    __syncthreads();

    if (k0 + 32 < K) {
      rA0 = *(const uint4*)(pA + k0 + 32);  rA1 = *(const uint4*)(pA + rowskip + k0 + 32);
      rW0 = *(const uint4*)(pW + k0 + 32);  rW1 = *(const uint4*)(pW + rowskip + k0 + 32);
      if constexpr (NSPLIT == 3) {
        rAl0 = *(const uint4*)(pAl + k0 + 32); rAl1 = *(const uint4*)(pAl + rowskip + k0 + 32);
        rWl0 = *(const uint4*)(pWl + k0 + 32); rWl1 = *(const uint4*)(pWl + rowskip + k0 + 32);
      }
    }

    f16x8 ah[4], wh[4], al[4], wl[4];
#pragma unroll
    for (int i = 0; i < 4; ++i) ah[i] = *(const f16x8*)&As[fA + i * 512];
#pragma unroll
    for (int j = 0; j < 4; ++j) wh[j] = *(const f16x8*)&Ws[fW + j * 512];
    if constexpr (NSPLIT == 3) {
#pragma unroll
      for (int i = 0; i < 4; ++i) al[i] = *(const f16x8*)&Als[fA + i * 512];
#pragma unroll
      for (int j = 0; j < 4; ++j) wl[j] = *(const f16x8*)&Wls[fW + j * 512];
    }

#pragma unroll
    for (int i = 0; i < 4; ++i)
#pragma unroll
      for (int j = 0; j < 4; ++j)
        acc[i][j] = __builtin_amdgcn_mfma_f32_16x16x32_f16(ah[i], wh[j], acc[i][j], 0, 0, 0);
    if constexpr (NSPLIT == 3) {
#pragma unroll
      for (int i = 0; i < 4; ++i)
#pragma unroll
        for (int j = 0; j < 4; ++j)
          acc[i][j] = __builtin_amdgcn_mfma_f32_16x16x32_f16(ah[i], wl[j], acc[i][j], 0, 0, 0);
#pragma unroll
      for (int i = 0; i < 4; ++i)
#pragma unroll
        for (int j = 0; j < 4; ++j)
          acc[i][j] = __builtin_amdgcn_mfma_f32_16x16x32_f16(al[i], wh[j], acc[i][j], 0, 0, 0);
    }
  }

  const int rr = (l >> 4) * 4;
  const int cc = l & 15;
#pragma unroll
  for (int j = 0; j < 4; ++j) {
    const int n = n0 + wn * 64 + j * 16 + cc;
    const float bv = bias[n];
#pragma unroll
    for (int i = 0; i < 4; ++i) {
      const int m = m0 + wm * 64 + i * 16 + rr;
#pragma unroll
      for (int r = 0; r < 4; ++r) {
        const float val = acc[i][j][r] * inv + bv;
        if constexpr (OUT == 0) {
          C[(size_t)(m + r) * N + n] = val;
        } else {
          const float sv = val * oscale;
          const f16 hh = (f16)sv;
          const f16 ll = (f16)(sv - (float)hh);
          Ch[(size_t)(m + r) * N + n] = hh;
          Cl[(size_t)(m + r) * N + n] = ll;
        }
      }
    }
  }
}

// ---------------------------------------------------------------------------
// Canonical split-3 QK^T accumulation for one 32x32 tile. Same op order in
// main loop and slow-path recompute => bit-identical results.
// ---------------------------------------------------------------------------
__device__ __forceinline__ f32x16 qk_accum(const f16x8 ah[4], const f16x8 al[4],
                                           const f16x8 qh_[4], const f16x8 ql_[4]) {
  f32x16 ca = (f32x16){};
  f32x16 cb = (f32x16){};
  ca = MFMA32(ah[0], qh_[0], ca);  cb = MFMA32(ah[1], qh_[1], cb);
  ca = MFMA32(ah[2], qh_[2], ca);  cb = MFMA32(ah[3], qh_[3], cb);
  ca = MFMA32(al[0], qh_[0], ca);  cb = MFMA32(al[1], qh_[1], cb);
  ca = MFMA32(al[2], qh_[2], ca);  cb = MFMA32(al[3], qh_[3], cb);
  ca = MFMA32(ah[0], ql_[0], ca);  cb = MFMA32(ah[1], ql_[1], cb);
  ca = MFMA32(ah[2], ql_[2], ca);  cb = MFMA32(ah[3], ql_[3], cb);
  return ca + cb;
}

__device__ __forceinline__ f32x16 qk_tile_global(const f16* __restrict__ kgh,
                                                 const f16* __restrict__ kgl,
                                                 int tt, int q5, int hi5,
                                                 const f16x8 qh_[4], const f16x8 ql_[4]) {
  const f16* kh = kgh + (size_t)(tt * 32 + q5) * DE + hi5 * 8;
  const f16* kl = kgl + (size_t)(tt * 32 + q5) * DE + hi5 * 8;
  f16x8 ah[4], al[4];
#pragma unroll
  for (int s = 0; s < 4; ++s) {
    ah[s] = *(const f16x8*)(kh + s * 16);
    al[s] = *(const f16x8*)(kl + s * 16);
  }
  return qk_accum(ah, al, qh_, ql_);
}

// ---------------------------------------------------------------------------
// Fused sparse attention v10 — GEMM-structured.
// Block = 128 q-rows (4 waves x 32 rows), loops 16 strips of 64 kv.
// K strip (hi+lo, 16KB) reg-staged into XOR-swizzled LDS, shared by all waves.
// Online per-element stats: m, cnt(==m), p1, p2, Z, H (vs m=0; v9-validated).
// Fast path (tk==1 && cnt<=2): out = (V[p1](+V[p2])) / (cnt + zeps).
// Slow path (tk>1 || cnt>2): wave-local MFMA-exact recompute from global.
// ---------------------------------------------------------------------------
__global__ __launch_bounds__(256, 3)
void attn_v10(const f16* __restrict__ qhb, const f16* __restrict__ qlb,
              const f16* __restrict__ khb, const f16* __restrict__ klb,
              const float* __restrict__ vb, f16* __restrict__ ob) {
  __shared__ f16 Ks[2][2][4096];     // [dbuf][hi/lo][64kv x 64d swizzled] 32KB
  __shared__ float4 stat[4][32];     // per wave/row: {wt|-1, p1, p2, cnt}
  __shared__ int   sidx[4][48];      // slow-path gather lists (per wave)
  __shared__ float sp[4][48];
  __shared__ int   scnt[4][2];

  const int phys = blockIdx.x;
  const int bid = (phys & 7) * 128 + (phys >> 3);   // 1024 blocks, bijective
  const int b  = bid >> 7;
  const int h  = (bid >> 4) & 7;
  const int qt = bid & 15;
  const int tid = threadIdx.x;
  const int w  = tid >> 6;
  const int l  = tid & 63;
  const int q5 = l & 31;
  const int hi5 = l >> 5;

  const float C2 = 1.44269504f / 4096.0f;

  // ---- persistent Q fragments (B operand): wave w owns rows qt*128+w*32+q5
  const int qrow = qt * 128 + w * 32 + q5;
  const f16* qpb = qhb + (size_t)(b * SQB + qrow) * DE + h * DH + hi5 * 8;
  const f16* qpl = qlb + (size_t)(b * SQB + qrow) * DE + h * DH + hi5 * 8;
  f16x8 qh_[4], ql_[4];
#pragma unroll
  for (int s = 0; s < 4; ++s) {
    qh_[s] = *(const f16x8*)(qpb + s * 16);
    ql_[s] = *(const f16x8*)(qpl + s * 16);
  }

  // ---- K global bases (this b,h)
  const f16* kgh = khb + (size_t)(b * SKVB) * DE + h * DH;
  const f16* kgl = klb + (size_t)(b * SKVB) * DE + h * DH;

  // ---- staging map: thread covers 16B slots tid and tid+256 per half.
  // slot s: kv = s>>3, ch = s&7. Straight coalesced loads; swizzled ds_write
  // (dest chunk = ch ^ (kv&7)); reads use the same XOR => involution.
  const int skv0 = tid >> 3;           // 0..31
  const int sch  = tid & 7;
  const int d_off0 = skv0 * 64 + ((sch ^ (skv0 & 7)) * 8);          // slot tid
  const int d_off1 = (32 + skv0) * 64 + ((sch ^ (skv0 & 7)) * 8);   // slot tid+256

  // ---- prologue: stage strip 0 into Ks[0]
  {
    const f16* shp = kgh + (size_t)skv0 * DE + sch * 8;
    const f16* slp = kgl + (size_t)skv0 * DE + sch * 8;
    uint4 a0 = *(const uint4*)(shp);
    uint4 a1 = *(const uint4*)(shp + 32 * DE);
    uint4 b0 = *(const uint4*)(slp);
    uint4 b1 = *(const uint4*)(slp + 32 * DE);
    *(uint4*)&Ks[0][0][d_off0] = a0;
    *(uint4*)&Ks[0][0][d_off1] = a1;
    *(uint4*)&Ks[0][1][d_off0] = b0;
    *(uint4*)&Ks[0][1][d_off1] = b1;
  }
  __syncthreads();

  // ---- online stats
  float m = -INFINITY, Z = 0.f, H = 0.f;
  int cnt = 0, p1 = -1, p2 = -1;

  for (int t = 0; t < 16; ++t) {
    const int cur = t & 1;
    const int nxt = cur ^ 1;
    // 1) issue next-strip loads early (latency hides under compute)
    uint4 La0, La1, Lb0, Lb1;
    const bool more = (t + 1 < 16);
    if (more) {
      const f16* shp = kgh + (size_t)((t + 1) * 64 + skv0) * DE + sch * 8;
      const f16* slp = kgl + (size_t)((t + 1) * 64 + skv0) * DE + sch * 8;
      La0 = *(const uint4*)(shp);
      La1 = *(const uint4*)(shp + 32 * DE);
      Lb0 = *(const uint4*)(slp);
      Lb1 = *(const uint4*)(slp + 32 * DE);
    }
    // 2) compute strip t from Ks[cur]
#pragma unroll
    for (int u = 0; u < 2; ++u) {
      const int kvl = u * 32 + q5;
      const int rowoff = kvl * 64;
      f16x8 ah[4], al[4];
#pragma unroll
      for (int s = 0; s < 4; ++s) {
        const int idx = rowoff + (((s * 2 + hi5) ^ (q5 & 7)) * 8);
        ah[s] = *(const f16x8*)&Ks[cur][0][idx];
        al[s] = *(const f16x8*)&Ks[cur][1][idx];
      }
      const f32x16 sv = qk_accum(ah, al, qh_, ql_);
      const int kvb = t * 64 + u * 32 + 4 * hi5;
#pragma unroll
      for (int r = 0; r < 16; ++r) {
        const float s = sv[r];
        const float e = __builtin_amdgcn_exp2f(s * C2);
        Z += e;
        H = fmaf(e, s, H);
        const int idx = kvb + (r & 3) + 8 * (r >> 2);
        if (s > m)      { m = s; cnt = 1; p1 = idx; p2 = -1; }
        else if (s == m) { cnt += 1; p2 = (p2 < 0) ? idx : p2; }
      }
    }
    // 3) write next strip, then barrier
    if (more) {
      *(uint4*)&Ks[nxt][0][d_off0] = La0;
      *(uint4*)&Ks[nxt][0][d_off1] = La1;
      *(uint4*)&Ks[nxt][1][d_off0] = Lb0;
      *(uint4*)&Ks[nxt][1][d_off1] = Lb1;
    }
    __syncthreads();
  }

  // ---- pair combine across halves (lanes l and l^32 share row q5)
  {
    const float mo = __shfl_xor(m, 32);
    const int co   = __shfl_xor(cnt, 32);
    const int p1o  = __shfl_xor(p1, 32);
    const int p2o  = __shfl_xor(p2, 32);
    Z += __shfl_xor(Z, 32);
    H += __shfl_xor(H, 32);
    if (mo > m)       { m = mo; cnt = co; p1 = p1o; p2 = p2o; }
    else if (mo == m) { p2 = (cnt == 1) ? p1o : p2; cnt += co; }
  }

  const float E = __logf(Z) - (H * (1.0f / 4096.0f)) / Z;
  int tk = (int)(32.0f * (1.0f - E));
  tk = tk < 1 ? 1 : (tk > 32 ? 32 : tk);
  const bool slowRow = (tk > 1) || (cnt > 2);
  const float zeps = 1e-8f * Z * __builtin_amdgcn_exp2f(-m * C2);
  const float wt = 1.0f / ((float)cnt + zeps);

  if (hi5 == 0)
    stat[w][q5] = make_float4(slowRow ? -1.0f : wt,
                              __int_as_float(p1),
                              __int_as_float(cnt == 2 ? p2 : -1),
                              (float)cnt);

  // ---- fast-path output: 1-2 V-row reads per row, fully coalesced
  {
    const size_t obase = (size_t)(b * SQB + qt * 128 + w * 32) * DE + h * DH + l;
    const float* vB = vb + (size_t)(b * SKVB) * DE + h * DH + l;
    for (int r = 0; r < 32; ++r) {
      const float4 st = stat[w][r];
      if (st.x >= 0.f) {
        const int pa = __float_as_int(st.y);
        const int pb = __float_as_int(st.z);
        float acc = vB[(size_t)pa * DE];
        if (pb >= 0) acc += vB[(size_t)pb * DE];
        ob[obase + (size_t)r * DE] = (f16)(acc * st.x);
      }
    }
  }

  // ---- slow path (correctness-only; ~never taken)
  {
    unsigned long long sb = __ballot(slowRow && hi5 == 0);
    while (sb != 0ull) {
      const int rr = (int)__builtin_ctzll(sb);
      sb &= sb - 1;
      const float mr = __shfl(m, rr);
      const int tkr  = __shfl(tk, rr);
      const int cntr = __shfl(cnt, rr);
      const float Zr = __shfl(Z, rr);
      float thr = mr;
      float rem = (float)tkr - (float)cntr;
      float curv = mr;
      int guard = 0;
      while (rem > 0.f && guard < 40) {
        ++guard;
        float nmx = -INFINITY;
        for (int tt = 0; tt < 32; ++tt) {
          const f32x16 sv = qk_tile_global(kgh, kgl, tt, q5, hi5, qh_, ql_);
          if (q5 == rr) {
#pragma unroll
            for (int r = 0; r < 16; ++r)
              nmx = (sv[r] < curv) ? fmaxf(nmx, sv[r]) : nmx;
          }
        }
        nmx = fmaxf(nmx, __shfl_xor(nmx, 32));
        const float cand = __shfl(nmx, rr);
        float cf = 0.f;
        for (int tt = 0; tt < 32; ++tt) {
          const f32x16 sv = qk_tile_global(kgh, kgl, tt, q5, hi5, qh_, ql_);
          if (q5 == rr) {
#pragma unroll
            for (int r = 0; r < 16; ++r) cf += (sv[r] == cand) ? 1.f : 0.f;
          }
        }
        cf += __shfl_xor(cf, 32);
        const float cfr = __shfl(cf, rr);
        if (cfr >= rem) { thr = cand; rem = 0.f; }
        else { rem -= cfr; curv = cand; }
      }
      // gather all s >= thr for row rr
      int myc = 0;
      for (int tt = 0; tt < 32; ++tt) {
        const f32x16 sv = qk_tile_global(kgh, kgl, tt, q5, hi5, qh_, ql_);
        if (q5 == rr) {
#pragma unroll
          for (int r = 0; r < 16; ++r) {
            if (sv[r] >= thr && myc < 24) {
              sidx[w][hi5 * 24 + myc] = tt * 32 + (r & 3) + 8 * (r >> 2) + 4 * hi5;
              sp[w][hi5 * 24 + myc] = __builtin_amdgcn_exp2f((sv[r] - mr) * C2);
              ++myc;
            }
          }
        }
      }
      if (q5 == rr) scnt[w][hi5] = myc;
      int c0 = scnt[w][0]; c0 = c0 > 24 ? 24 : c0;
      int c1 = scnt[w][1]; c1 = c1 > 24 ? 24 : c1;
      float acc = 0.f, ps = 0.f;
      const float* vB = vb + (size_t)(b * SKVB) * DE + h * DH + l;
      for (int e = 0; e < c0; ++e) {
        const int kv = sidx[w][e]; const float p = sp[w][e];
        ps += p; acc = fmaf(p, vB[(size_t)kv * DE], acc);
      }
      for (int e = 0; e < c1; ++e) {
        const int kv = sidx[w][24 + e]; const float p = sp[w][24 + e];
        ps += p; acc = fmaf(p, vB[(size_t)kv * DE], acc);
      }
      const float zepsr = 1e-8f * Zr * __builtin_amdgcn_exp2f(-mr * C2);
      const float o = acc / (ps + zepsr);
      ob[(size_t)(b * SQB + qt * 128 + w * 32 + rr) * DE + h * DH + l] = (f16)o;
    }
  }
}

// ---------------------------------------------------------------------------
extern "C" void kernel_launch(void* const* d_in, const int* in_sizes, int n_in,
                              void* d_out, int out_size, void* d_ws, size_t ws_size,
                              hipStream_t stream) {
  const float* x  = (const float*)d_in[0];
  const float* y  = (const float*)d_in[1];
  const float* wq = (const float*)d_in[2];
  const float* bq = (const float*)d_in[3];
  const float* wk = (const float*)d_in[4];
  const float* bk = (const float*)d_in[5];
  const float* wv = (const float*)d_in[6];
  const float* bv = (const float*)d_in[7];
  const float* wo = (const float*)d_in[8];
  const float* bo = (const float*)d_in[9];
  float* out = (float*)d_out;

  char* ws = (char*)d_ws;
  const size_t MiB = 1048576;

  f16* xh  = (f16*)(ws);                       // 16 MiB
  f16* xl  = (f16*)(ws + 16 * MiB);            // 16
  f16* yh  = (f16*)(ws + 32 * MiB);            // 12
  f16* yl  = (f16*)(ws + 44 * MiB);            // 12
  f16* qh  = (f16*)(ws + 56 * MiB);            // 16
  f16* ql  = (f16*)(ws + 72 * MiB);            // 16
  f16* kh  = (f16*)(ws + 88 * MiB);            // 8
  f16* kl  = (f16*)(ws + 96 * MiB);            // 8
  float* v = (float*)(ws + 104 * MiB);         // 16 (f32)
  f16* ao  = (f16*)(ws + 120 * MiB);           // 16
  f16* wqh = (f16*)(ws + 136 * MiB);
  f16* wql = (f16*)(ws + 136 * MiB + 524288);
  f16* wkh = (f16*)(ws + 137 * MiB);
  f16* wkl = (f16*)(ws + 137 * MiB + 786432);
  f16* wvh = (f16*)(ws + 138 * MiB + 524288);
  f16* wvl = (f16*)(ws + 139 * MiB + 262144);
  f16* woh = (f16*)(ws + 140 * MiB);
  f16* wol = (f16*)(ws + 140 * MiB + 524288);

  dim3 blk(256);
  const float WS = 2048.0f, IWS = 1.0f / 2048.0f;

  split_f16<<<dim3(8192), blk, 0, stream>>>(x, xh, xl, 2097152, 1.0f);
  split_f16<<<dim3(6144), blk, 0, stream>>>(y, yh, yl, 1572864, 1.0f);
  split_f16<<<dim3(256),  blk, 0, stream>>>(wq, wqh, wql, 65536, WS);
  split_f16<<<dim3(384),  blk, 0, stream>>>(wk, wkh, wkl, 98304, WS);
  split_f16<<<dim3(384),  blk, 0, stream>>>(wv, wvh, wvl, 98304, 1.0f);
  split_f16<<<dim3(256),  blk, 0, stream>>>(wo, woh, wol, 65536, 1.0f);

  // Q-proj -> split pair scaled x8  (q_true * 0.125 * 64)
  gemm_f16<3, 1><<<dim3(4, 128), blk, 0, stream>>>(xh, xl, wqh, wql, bq,
      nullptr, qh, ql, 16384, 512, 512, IWS, 8.0f);
  // K-proj -> split pair scaled x64
  gemm_f16<3, 1><<<dim3(4, 64), blk, 0, stream>>>(yh, yl, wkh, wkl, bk,
      nullptr, kh, kl, 8192, 512, 768, IWS, 64.0f);
  // V-proj -> f32
  gemm_f16<1, 0><<<dim3(4, 64), blk, 0, stream>>>(yh, nullptr, wvh, nullptr, bv,
      v, nullptr, nullptr, 8192, 512, 768, 1.0f, 1.0f);

  attn_v10<<<dim3(1024), blk, 0, stream>>>(qh, ql, kh, kl, v, ao);

  // O-proj
  gemm_f16<1, 0><<<dim3(4, 128), blk, 0, stream>>>(ao, nullptr, woh, nullptr, bo,
      out, nullptr, nullptr, 16384, 512, 512, 1.0f, 1.0f);
}

// Round 12
// 221.051 us; speedup vs baseline: 2.1746x; 1.1577x over previous
//
#include <hip/hip_runtime.h>
#include <cstdint>
#include <cmath>

#define DH 64
#define SQB 2048
#define SKVB 1024
#define DE 512

typedef _Float16 f16;
typedef _Float16 f16x8 __attribute__((ext_vector_type(8)));
typedef float f32x4 __attribute__((ext_vector_type(4)));
typedef float f32x16 __attribute__((ext_vector_type(16)));

#define MFMA32(A, B, C) __builtin_amdgcn_mfma_f32_32x32x16_f16(A, B, C, 0, 0, 0)

// ---------------------------------------------------------------------------
// Split fp32 -> (hi, lo) fp16 pair, optional pre-scale.
// ---------------------------------------------------------------------------
__global__ __launch_bounds__(256)
void split_f16(const float* __restrict__ in, f16* __restrict__ hi,
               f16* __restrict__ lo, int n4, float scale) {
  const int i = blockIdx.x * 256 + threadIdx.x;
  if (i >= n4) return;
  float4 v = ((const float4*)in)[i];
  v.x *= scale; v.y *= scale; v.z *= scale; v.w *= scale;
  f16 h0 = (f16)v.x, h1 = (f16)v.y, h2 = (f16)v.z, h3 = (f16)v.w;
  f16 l0 = (f16)(v.x - (float)h0), l1 = (f16)(v.y - (float)h1);
  f16 l2 = (f16)(v.z - (float)h2), l3 = (f16)(v.w - (float)h3);
  f16 hb[4] = {h0, h1, h2, h3};
  f16 lb[4] = {l0, l1, l2, l3};
  ((uint2*)hi)[i] = *(const uint2*)hb;
  ((uint2*)lo)[i] = *(const uint2*)lb;
}

// ---------------------------------------------------------------------------
// MFMA f16 GEMM (validated R4/R5 core). OUT=0: C fp32. OUT=1: split-f16 pair.
// ---------------------------------------------------------------------------
template <int NSPLIT, int OUT>
__global__ __launch_bounds__(256, 2)
void gemm_f16(const f16* __restrict__ Ah, const f16* __restrict__ Al,
              const f16* __restrict__ Wh, const f16* __restrict__ Wl,
              const float* __restrict__ bias, float* __restrict__ C,
              f16* __restrict__ Ch, f16* __restrict__ Cl,
              int M, int N, int K, float inv, float oscale) {
  __shared__ f16 smem[(NSPLIT == 3 ? 4 : 2) * 4096];
  f16* As  = smem;
  f16* Als = (NSPLIT == 3) ? smem + 4096 : nullptr;
  f16* Ws  = smem + (NSPLIT == 3 ? 8192 : 4096);
  f16* Wls = (NSPLIT == 3) ? smem + 12288 : nullptr;

  const int tid = threadIdx.x;
  const int w = tid >> 6;
  const int l = tid & 63;
  const int wm = w >> 1, wn = w & 1;
  const int m0 = blockIdx.y * 128;
  const int n0 = blockIdx.x * 128;

  const int srow = tid >> 2;
  const int schk = tid & 3;
  const f16* pA  = Ah + (size_t)(m0 + srow) * K + schk * 8;
  const f16* pW  = Wh + (size_t)(n0 + srow) * K + schk * 8;
  const f16* pAl = (NSPLIT == 3) ? Al + (size_t)(m0 + srow) * K + schk * 8 : nullptr;
  const f16* pWl = (NSPLIT == 3) ? Wl + (size_t)(n0 + srow) * K + schk * 8 : nullptr;
  const size_t rowskip = (size_t)64 * K;

  const int d0 = srow * 32 + ((schk ^ (srow & 3)) * 8);
  const int fbase = (l & 15) * 32 + (((l >> 4) ^ (l & 3)) * 8);
  const int fA = wm * 2048 + fbase;
  const int fW = wn * 2048 + fbase;

  f32x4 acc[4][4] = {};
  uint4 rA0, rA1, rW0, rW1, rAl0, rAl1, rWl0, rWl1;

  rA0 = *(const uint4*)(pA);            rA1 = *(const uint4*)(pA + rowskip);
  rW0 = *(const uint4*)(pW);            rW1 = *(const uint4*)(pW + rowskip);
  if constexpr (NSPLIT == 3) {
    rAl0 = *(const uint4*)(pAl);        rAl1 = *(const uint4*)(pAl + rowskip);
    rWl0 = *(const uint4*)(pWl);        rWl1 = *(const uint4*)(pWl + rowskip);
  }

  for (int k0 = 0; k0 < K; k0 += 32) {
    __syncthreads();
    *(uint4*)&As[d0] = rA0;  *(uint4*)&As[d0 + 2048] = rA1;
    *(uint4*)&Ws[d0] = rW0;  *(uint4*)&Ws[d0 + 2048] = rW1;
    if constexpr (NSPLIT == 3) {
      *(uint4*)&Als[d0] = rAl0;  *(uint4*)&Als[d0 + 2048] = rAl1;
      *(uint4*)&Wls[d0] = rWl0;  *(uint4*)&Wls[d0 + 2048] = rWl1;
    }
    __syncthreads();

    if (k0 + 32 < K) {
      rA0 = *(const uint4*)(pA + k0 + 32);  rA1 = *(const uint4*)(pA + rowskip + k0 + 32);
      rW0 = *(const uint4*)(pW + k0 + 32);  rW1 = *(const uint4*)(pW + rowskip + k0 + 32);
      if constexpr (NSPLIT == 3) {
        rAl0 = *(const uint4*)(pAl + k0 + 32); rAl1 = *(const uint4*)(pAl + rowskip + k0 + 32);
        rWl0 = *(const uint4*)(pWl + k0 + 32); rWl1 = *(const uint4*)(pWl + rowskip + k0 + 32);
      }
    }

    f16x8 ah[4], wh[4], al[4], wl[4];
#pragma unroll
    for (int i = 0; i < 4; ++i) ah[i] = *(const f16x8*)&As[fA + i * 512];
#pragma unroll
    for (int j = 0; j < 4; ++j) wh[j] = *(const f16x8*)&Ws[fW + j * 512];
    if constexpr (NSPLIT == 3) {
#pragma unroll
      for (int i = 0; i < 4; ++i) al[i] = *(const f16x8*)&Als[fA + i * 512];
#pragma unroll
      for (int j = 0; j < 4; ++j) wl[j] = *(const f16x8*)&Wls[fW + j * 512];
    }

#pragma unroll
    for (int i = 0; i < 4; ++i)
#pragma unroll
      for (int j = 0; j < 4; ++j)
        acc[i][j] = __builtin_amdgcn_mfma_f32_16x16x32_f16(ah[i], wh[j], acc[i][j], 0, 0, 0);
    if constexpr (NSPLIT == 3) {
#pragma unroll
      for (int i = 0; i < 4; ++i)
#pragma unroll
        for (int j = 0; j < 4; ++j)
          acc[i][j] = __builtin_amdgcn_mfma_f32_16x16x32_f16(ah[i], wl[j], acc[i][j], 0, 0, 0);
#pragma unroll
      for (int i = 0; i < 4; ++i)
#pragma unroll
        for (int j = 0; j < 4; ++j)
          acc[i][j] = __builtin_amdgcn_mfma_f32_16x16x32_f16(al[i], wh[j], acc[i][j], 0, 0, 0);
    }
  }

  const int rr = (l >> 4) * 4;
  const int cc = l & 15;
#pragma unroll
  for (int j = 0; j < 4; ++j) {
    const int n = n0 + wn * 64 + j * 16 + cc;
    const float bv = bias[n];
#pragma unroll
    for (int i = 0; i < 4; ++i) {
      const int m = m0 + wm * 64 + i * 16 + rr;
#pragma unroll
      for (int r = 0; r < 4; ++r) {
        const float val = acc[i][j][r] * inv + bv;
        if constexpr (OUT == 0) {
          C[(size_t)(m + r) * N + n] = val;
        } else {
          const float sv = val * oscale;
          const f16 hh = (f16)sv;
          const f16 ll = (f16)(sv - (float)hh);
          Ch[(size_t)(m + r) * N + n] = hh;
          Cl[(size_t)(m + r) * N + n] = ll;
        }
      }
    }
  }
}

// ---------------------------------------------------------------------------
// Canonical split-3 QK^T accumulation for one 32x32 tile. Same op order in
// main loop and slow-path recompute => bit-identical results.
// ---------------------------------------------------------------------------
__device__ __forceinline__ f32x16 qk_accum(const f16x8 ah[4], const f16x8 al[4],
                                           const f16x8 qh_[4], const f16x8 ql_[4]) {
  f32x16 ca = (f32x16){};
  f32x16 cb = (f32x16){};
  ca = MFMA32(ah[0], qh_[0], ca);  cb = MFMA32(ah[1], qh_[1], cb);
  ca = MFMA32(ah[2], qh_[2], ca);  cb = MFMA32(ah[3], qh_[3], cb);
  ca = MFMA32(al[0], qh_[0], ca);  cb = MFMA32(al[1], qh_[1], cb);
  ca = MFMA32(al[2], qh_[2], ca);  cb = MFMA32(al[3], qh_[3], cb);
  ca = MFMA32(ah[0], ql_[0], ca);  cb = MFMA32(ah[1], ql_[1], cb);
  ca = MFMA32(ah[2], ql_[2], ca);  cb = MFMA32(ah[3], ql_[3], cb);
  return ca + cb;
}

__device__ __forceinline__ f32x16 qk_tile_global(const f16* __restrict__ kgh,
                                                 const f16* __restrict__ kgl,
                                                 int tt, int q5, int hi5,
                                                 const f16x8 qh_[4], const f16x8 ql_[4]) {
  const f16* kh = kgh + (size_t)(tt * 32 + q5) * DE + hi5 * 8;
  const f16* kl = kgl + (size_t)(tt * 32 + q5) * DE + hi5 * 8;
  f16x8 ah[4], al[4];
#pragma unroll
  for (int s = 0; s < 4; ++s) {
    ah[s] = *(const f16x8*)(kh + s * 16);
    al[s] = *(const f16x8*)(kl + s * 16);
  }
  return qk_accum(ah, al, qh_, ql_);
}

// ---------------------------------------------------------------------------
// Fused sparse attention v11 — v10 GEMM structure + per-TILE max tracking.
// Block = 128 q-rows (4 waves x 32 rows), 16 strips of 64 kv via swizzled LDS.
// Per 16-elem tile result: Z/H accumulate + fmax tree; winning tile's values
// snapshotted (16 cndmask) instead of per-element position bookkeeping.
// Positions/ties recovered post-loop from the snapshot. Cross-tile tie or
// tk>1 or cnt>2 -> full-recompute slow path (exact, ~never taken).
// ---------------------------------------------------------------------------
__global__ __launch_bounds__(256, 3)
void attn_v11(const f16* __restrict__ qhb, const f16* __restrict__ qlb,
              const f16* __restrict__ khb, const f16* __restrict__ klb,
              const float* __restrict__ vb, f16* __restrict__ ob) {
  __shared__ f16 Ks[2][2][4096];     // [dbuf][hi/lo][64kv x 64d swizzled] 32KB
  __shared__ float4 stat[4][32];     // per wave/row: {wt|-1, pa, pb, cnt}
  __shared__ int   sidx[4][48];      // slow-path gather lists (per wave)
  __shared__ float sp[4][48];
  __shared__ int   scnt[4][2];

  const int phys = blockIdx.x;
  const int bid = (phys & 7) * 128 + (phys >> 3);   // 1024 blocks, bijective
  const int b  = bid >> 7;
  const int h  = (bid >> 4) & 7;
  const int qt = bid & 15;
  const int tid = threadIdx.x;
  const int w  = tid >> 6;
  const int l  = tid & 63;
  const int q5 = l & 31;
  const int hi5 = l >> 5;

  const float C2 = 1.44269504f / 4096.0f;

  // ---- persistent Q fragments (B operand): wave w owns rows qt*128+w*32+q5
  const int qrow = qt * 128 + w * 32 + q5;
  const f16* qpb = qhb + (size_t)(b * SQB + qrow) * DE + h * DH + hi5 * 8;
  const f16* qpl = qlb + (size_t)(b * SQB + qrow) * DE + h * DH + hi5 * 8;
  f16x8 qh_[4], ql_[4];
#pragma unroll
  for (int s = 0; s < 4; ++s) {
    qh_[s] = *(const f16x8*)(qpb + s * 16);
    ql_[s] = *(const f16x8*)(qpl + s * 16);
  }

  // ---- K global bases (this b,h)
  const f16* kgh = khb + (size_t)(b * SKVB) * DE + h * DH;
  const f16* kgl = klb + (size_t)(b * SKVB) * DE + h * DH;

  // ---- staging map (v10-validated): swizzled ds_write, same XOR on read
  const int skv0 = tid >> 3;           // 0..31
  const int sch  = tid & 7;
  const int d_off0 = skv0 * 64 + ((sch ^ (skv0 & 7)) * 8);
  const int d_off1 = (32 + skv0) * 64 + ((sch ^ (skv0 & 7)) * 8);

  // ---- prologue: stage strip 0 into Ks[0]
  {
    const f16* shp = kgh + (size_t)skv0 * DE + sch * 8;
    const f16* slp = kgl + (size_t)skv0 * DE + sch * 8;
    uint4 a0 = *(const uint4*)(shp);
    uint4 a1 = *(const uint4*)(shp + 32 * DE);
    uint4 b0 = *(const uint4*)(slp);
    uint4 b1 = *(const uint4*)(slp + 32 * DE);
    *(uint4*)&Ks[0][0][d_off0] = a0;
    *(uint4*)&Ks[0][0][d_off1] = a1;
    *(uint4*)&Ks[0][1][d_off0] = b0;
    *(uint4*)&Ks[0][1][d_off1] = b1;
  }
  __syncthreads();

  // ---- online stats (per-tile granularity)
  float m = -INFINITY, Z = 0.f, H = 0.f;
  int mt = 0;
  bool tie = false;
  f32x16 best = (f32x16){};

  for (int t = 0; t < 16; ++t) {
    const int cur = t & 1;
    const int nxt = cur ^ 1;
    uint4 La0, La1, Lb0, Lb1;
    const bool more = (t + 1 < 16);
    if (more) {
      const f16* shp = kgh + (size_t)((t + 1) * 64 + skv0) * DE + sch * 8;
      const f16* slp = kgl + (size_t)((t + 1) * 64 + skv0) * DE + sch * 8;
      La0 = *(const uint4*)(shp);
      La1 = *(const uint4*)(shp + 32 * DE);
      Lb0 = *(const uint4*)(slp);
      Lb1 = *(const uint4*)(slp + 32 * DE);
    }
#pragma unroll
    for (int u = 0; u < 2; ++u) {
      const int kvl = u * 32 + q5;
      const int rowoff = kvl * 64;
      f16x8 ah[4], al[4];
#pragma unroll
      for (int s = 0; s < 4; ++s) {
        const int idx = rowoff + (((s * 2 + hi5) ^ (q5 & 7)) * 8);
        ah[s] = *(const f16x8*)&Ks[cur][0][idx];
        al[s] = *(const f16x8*)&Ks[cur][1][idx];
      }
      const f32x16 sv = qk_accum(ah, al, qh_, ql_);
      // Z/H + tile max (fmax tree)
      float t0 = fmaxf(fmaxf(sv[0], sv[1]), fmaxf(sv[2], sv[3]));
      float t1 = fmaxf(fmaxf(sv[4], sv[5]), fmaxf(sv[6], sv[7]));
      float t2 = fmaxf(fmaxf(sv[8], sv[9]), fmaxf(sv[10], sv[11]));
      float t3 = fmaxf(fmaxf(sv[12], sv[13]), fmaxf(sv[14], sv[15]));
      const float tmax = fmaxf(fmaxf(t0, t1), fmaxf(t2, t3));
#pragma unroll
      for (int r = 0; r < 16; ++r) {
        const float s = sv[r];
        const float e = __builtin_amdgcn_exp2f(s * C2);
        Z += e;
        H = fmaf(e, s, H);
      }
      const bool upd = (tmax > m);
      tie = upd ? false : (tie || (tmax == m));
      if (upd) { m = tmax; mt = t * 2 + u; }
#pragma unroll
      for (int r = 0; r < 16; ++r) best[r] = upd ? sv[r] : best[r];
    }
    if (more) {
      *(uint4*)&Ks[nxt][0][d_off0] = La0;
      *(uint4*)&Ks[nxt][0][d_off1] = La1;
      *(uint4*)&Ks[nxt][1][d_off0] = Lb0;
      *(uint4*)&Ks[nxt][1][d_off1] = Lb1;
    }
    __syncthreads();
  }

  // ---- pair combine of m/Z/H/tie (lanes l and l^32 share row q5)
  const float mo = __shfl_xor(m, 32);
  const int tieo = __shfl_xor(tie ? 1 : 0, 32);
  Z += __shfl_xor(Z, 32);
  H += __shfl_xor(H, 32);
  const float mc = fmaxf(m, mo);
  const bool tiec = (m > mo) ? tie : ((mo > m) ? (tieo != 0) : (tie || tieo != 0));

  // ---- scan my snapshot for positions of ==mc (my half, my winning tile)
  int c = 0, p1 = -1, p2 = -1;
#pragma unroll
  for (int r = 0; r < 16; ++r) {
    if (best[r] == mc) {
      const int pos = mt * 32 + (r & 3) + 8 * (r >> 2) + 4 * hi5;
      p2 = (c == 1) ? pos : p2;
      p1 = (c == 0) ? pos : p1;
      ++c;
    }
  }
  const int co  = __shfl_xor(c, 32);
  const int p1o = __shfl_xor(p1, 32);
  const int p2o = __shfl_xor(p2, 32);
  const int ct = c + co;
  const int pa = (c > 0) ? p1 : p1o;
  const int pb = (c >= 2) ? p2 : ((c == 1) ? ((co > 0) ? p1o : -1)
                                           : ((co >= 2) ? p2o : -1));

  const float E = __logf(Z) - (H * (1.0f / 4096.0f)) / Z;
  int tk = (int)(32.0f * (1.0f - E));
  tk = tk < 1 ? 1 : (tk > 32 ? 32 : tk);
  const bool slowRow = (tk > 1) || tiec || (ct > 2);
  const float zeps = 1e-8f * Z * __builtin_amdgcn_exp2f(-mc * C2);
  const float wt = 1.0f / ((float)ct + zeps);

  if (hi5 == 0)
    stat[w][q5] = make_float4(slowRow ? -1.0f : wt,
                              __int_as_float(pa),
                              __int_as_float(ct == 2 ? pb : -1),
                              (float)ct);

  // ---- fast-path output: 1-2 V-row reads per row, fully coalesced
  {
    const size_t obase = (size_t)(b * SQB + qt * 128 + w * 32) * DE + h * DH + l;
    const float* vB = vb + (size_t)(b * SKVB) * DE + h * DH + l;
    for (int r = 0; r < 32; ++r) {
      const float4 st = stat[w][r];
      if (st.x >= 0.f) {
        const int ppa = __float_as_int(st.y);
        const int ppb = __float_as_int(st.z);
        float acc = vB[(size_t)ppa * DE];
        if (ppb >= 0) acc += vB[(size_t)ppb * DE];
        ob[obase + (size_t)r * DE] = (f16)(acc * st.x);
      }
    }
  }

  // ---- slow path (correctness-only; ~never taken). Full recompute.
  {
    unsigned long long sb = __ballot(slowRow && hi5 == 0);
    while (sb != 0ull) {
      const int rr = (int)__builtin_ctzll(sb);
      sb &= sb - 1;
      const float mr = __shfl(mc, rr);
      const int tkr  = __shfl(tk, rr);
      const float Zr = __shfl(Z, rr);
      float thr = mr;
      float rem = (float)tkr;
      float cand = mr;
      int guard = 0;
      bool done = false;
      while (!done && guard < 40) {
        ++guard;
        float cf = 0.f, nmx = -INFINITY;
        for (int tt = 0; tt < 32; ++tt) {
          const f32x16 sv = qk_tile_global(kgh, kgl, tt, q5, hi5, qh_, ql_);
          if (q5 == rr) {
#pragma unroll
            for (int r = 0; r < 16; ++r) {
              cf += (sv[r] == cand) ? 1.f : 0.f;
              nmx = (sv[r] < cand) ? fmaxf(nmx, sv[r]) : nmx;
            }
          }
        }
        cf += __shfl_xor(cf, 32);
        nmx = fmaxf(nmx, __shfl_xor(nmx, 32));
        const float cfr = __shfl(cf, rr);
        const float nmr = __shfl(nmx, rr);
        if (cfr >= rem) { thr = cand; done = true; }
        else { rem -= cfr; cand = nmr; }
      }
      // gather all s >= thr for row rr
      int myc = 0;
      for (int tt = 0; tt < 32; ++tt) {
        const f32x16 sv = qk_tile_global(kgh, kgl, tt, q5, hi5, qh_, ql_);
        if (q5 == rr) {
#pragma unroll
          for (int r = 0; r < 16; ++r) {
            if (sv[r] >= thr && myc < 24) {
              sidx[w][hi5 * 24 + myc] = tt * 32 + (r & 3) + 8 * (r >> 2) + 4 * hi5;
              sp[w][hi5 * 24 + myc] = __builtin_amdgcn_exp2f((sv[r] - mr) * C2);
              ++myc;
            }
          }
        }
      }
      if (q5 == rr) scnt[w][hi5] = myc;
      int c0 = scnt[w][0]; c0 = c0 > 24 ? 24 : c0;
      int c1 = scnt[w][1]; c1 = c1 > 24 ? 24 : c1;
      float acc = 0.f, ps = 0.f;
      const float* vB = vb + (size_t)(b * SKVB) * DE + h * DH + l;
      for (int e = 0; e < c0; ++e) {
        const int kv = sidx[w][e]; const float p = sp[w][e];
        ps += p; acc = fmaf(p, vB[(size_t)kv * DE], acc);
      }
      for (int e = 0; e < c1; ++e) {
        const int kv = sidx[w][24 + e]; const float p = sp[w][24 + e];
        ps += p; acc = fmaf(p, vB[(size_t)kv * DE], acc);
      }
      const float zepsr = 1e-8f * Zr * __builtin_amdgcn_exp2f(-mr * C2);
      const float o = acc / (ps + zepsr);
      ob[(size_t)(b * SQB + qt * 128 + w * 32 + rr) * DE + h * DH + l] = (f16)o;
    }
  }
}

// ---------------------------------------------------------------------------
extern "C" void kernel_launch(void* const* d_in, const int* in_sizes, int n_in,
                              void* d_out, int out_size, void* d_ws, size_t ws_size,
                              hipStream_t stream) {
  const float* x  = (const float*)d_in[0];
  const float* y  = (const float*)d_in[1];
  const float* wq = (const float*)d_in[2];
  const float* bq = (const float*)d_in[3];
  const float* wk = (const float*)d_in[4];
  const float* bk = (const float*)d_in[5];
  const float* wv = (const float*)d_in[6];
  const float* bv = (const float*)d_in[7];
  const float* wo = (const float*)d_in[8];
  const float* bo = (const float*)d_in[9];
  float* out = (float*)d_out;

  char* ws = (char*)d_ws;
  const size_t MiB = 1048576;

  f16* xh  = (f16*)(ws);                       // 16 MiB
  f16* xl  = (f16*)(ws + 16 * MiB);            // 16
  f16* yh  = (f16*)(ws + 32 * MiB);            // 12
  f16* yl  = (f16*)(ws + 44 * MiB);            // 12
  f16* qh  = (f16*)(ws + 56 * MiB);            // 16
  f16* ql  = (f16*)(ws + 72 * MiB);            // 16
  f16* kh  = (f16*)(ws + 88 * MiB);            // 8
  f16* kl  = (f16*)(ws + 96 * MiB);            // 8
  float* v = (float*)(ws + 104 * MiB);         // 16 (f32)
  f16* ao  = (f16*)(ws + 120 * MiB);           // 16
  f16* wqh = (f16*)(ws + 136 * MiB);
  f16* wql = (f16*)(ws + 136 * MiB + 524288);
  f16* wkh = (f16*)(ws + 137 * MiB);
  f16* wkl = (f16*)(ws + 137 * MiB + 786432);
  f16* wvh = (f16*)(ws + 138 * MiB + 524288);
  f16* wvl = (f16*)(ws + 139 * MiB + 262144);
  f16* woh = (f16*)(ws + 140 * MiB);
  f16* wol = (f16*)(ws + 140 * MiB + 524288);

  dim3 blk(256);
  const float WS = 2048.0f, IWS = 1.0f / 2048.0f;

  split_f16<<<dim3(8192), blk, 0, stream>>>(x, xh, xl, 2097152, 1.0f);
  split_f16<<<dim3(6144), blk, 0, stream>>>(y, yh, yl, 1572864, 1.0f);
  split_f16<<<dim3(256),  blk, 0, stream>>>(wq, wqh, wql, 65536, WS);
  split_f16<<<dim3(384),  blk, 0, stream>>>(wk, wkh, wkl, 98304, WS);
  split_f16<<<dim3(384),  blk, 0, stream>>>(wv, wvh, wvl, 98304, 1.0f);
  split_f16<<<dim3(256),  blk, 0, stream>>>(wo, woh, wol, 65536, 1.0f);

  // Q-proj -> split pair scaled x8  (q_true * 0.125 * 64)
  gemm_f16<3, 1><<<dim3(4, 128), blk, 0, stream>>>(xh, xl, wqh, wql, bq,
      nullptr, qh, ql, 16384, 512, 512, IWS, 8.0f);
  // K-proj -> split pair scaled x64
  gemm_f16<3, 1><<<dim3(4, 64), blk, 0, stream>>>(yh, yl, wkh, wkl, bk,
      nullptr, kh, kl, 8192, 512, 768, IWS, 64.0f);
  // V-proj -> f32
  gemm_f16<1, 0><<<dim3(4, 64), blk, 0, stream>>>(yh, nullptr, wvh, nullptr, bv,
      v, nullptr, nullptr, 8192, 512, 768, 1.0f, 1.0f);

  attn_v11<<<dim3(1024), blk, 0, stream>>>(qh, ql, kh, kl, v, ao);

  // O-proj
  gemm_f16<1, 0><<<dim3(4, 128), blk, 0, stream>>>(ao, nullptr, woh, nullptr, bo,
      out, nullptr, nullptr, 16384, 512, 512, 1.0f, 1.0f);
}

// Round 13
// 212.773 us; speedup vs baseline: 2.2592x; 1.0389x over previous
//
#include <hip/hip_runtime.h>
#include <cstdint>
#include <cmath>

#define DH 64
#define SQB 2048
#define SKVB 1024
#define DE 512

typedef _Float16 f16;
typedef _Float16 f16x8 __attribute__((ext_vector_type(8)));
typedef float f32x4 __attribute__((ext_vector_type(4)));
typedef float f32x16 __attribute__((ext_vector_type(16)));
typedef unsigned int u32;

#define MFMA32(A, B, C) __builtin_amdgcn_mfma_f32_32x32x16_f16(A, B, C, 0, 0, 0)

// ---------------------------------------------------------------------------
// async global->LDS 16B (wave-uniform LDS base + lane*16; global addr per-lane)
// ---------------------------------------------------------------------------
__device__ __forceinline__ void gl16(const f16* g, f16* l) {
  __builtin_amdgcn_global_load_lds(
      (const __attribute__((address_space(1))) u32*)g,
      (__attribute__((address_space(3))) u32*)l, 16, 0, 0);
}

// ---------------------------------------------------------------------------
// split helpers
// ---------------------------------------------------------------------------
__device__ __forceinline__ void do_split(const float* __restrict__ in,
                                         f16* __restrict__ hi, f16* __restrict__ lo,
                                         int i, float scale) {
  float4 v = ((const float4*)in)[i];
  v.x *= scale; v.y *= scale; v.z *= scale; v.w *= scale;
  f16 h0 = (f16)v.x, h1 = (f16)v.y, h2 = (f16)v.z, h3 = (f16)v.w;
  f16 l0 = (f16)(v.x - (float)h0), l1 = (f16)(v.y - (float)h1);
  f16 l2 = (f16)(v.z - (float)h2), l3 = (f16)(v.w - (float)h3);
  f16 hb[4] = {h0, h1, h2, h3};
  f16 lb[4] = {l0, l1, l2, l3};
  ((uint2*)hi)[i] = *(const uint2*)hb;
  ((uint2*)lo)[i] = *(const uint2*)lb;
}

// x + y in one launch (scale 1.0 both)
__global__ __launch_bounds__(256)
void split2(const float* __restrict__ a, f16* __restrict__ ah, f16* __restrict__ al, int na,
            const float* __restrict__ b, f16* __restrict__ bh, f16* __restrict__ bl, int nb) {
  const int i = blockIdx.x * 256 + threadIdx.x;
  if (i < na) do_split(a, ah, al, i, 1.0f);
  else if (i < na + nb) do_split(b, bh, bl, i - na, 1.0f);
}

// all four weights in one launch
__global__ __launch_bounds__(256)
void split4(const float* __restrict__ a, f16* __restrict__ ah, f16* __restrict__ al, int na, float sa,
            const float* __restrict__ b, f16* __restrict__ bh, f16* __restrict__ bl, int nb, float sb,
            const float* __restrict__ c, f16* __restrict__ ch, f16* __restrict__ cl, int nc, float sc,
            const float* __restrict__ d, f16* __restrict__ dh, f16* __restrict__ dl, int nd, float sd) {
  int i = blockIdx.x * 256 + threadIdx.x;
  if (i < na) { do_split(a, ah, al, i, sa); return; }
  i -= na;
  if (i < nb) { do_split(b, bh, bl, i, sb); return; }
  i -= nb;
  if (i < nc) { do_split(c, ch, cl, i, sc); return; }
  i -= nc;
  if (i < nd) do_split(d, dh, dl, i, sd);
}

// ---------------------------------------------------------------------------
// MFMA f16 GEMM — R4-validated math, staging switched to global_load_lds(16)
// with pre-swizzled global source (LDS content bit-identical to prior layout).
// Double-buffered, one barrier per K-step.
// OUT=0: C fp32. OUT=1: split-f16 pair of (C * oscale).
// ---------------------------------------------------------------------------
template <int NSPLIT, int OUT>
__global__ __launch_bounds__(256, 2)
void gemm_f16(const f16* __restrict__ Ah, const f16* __restrict__ Al,
              const f16* __restrict__ Wh, const f16* __restrict__ Wl,
              const float* __restrict__ bias, float* __restrict__ C,
              f16* __restrict__ Ch, f16* __restrict__ Cl,
              int M, int N, int K, float inv, float oscale) {
  constexpr int NPART = (NSPLIT == 3) ? 4 : 2;
  __shared__ f16 smem[2][NPART * 4096];   // parts: As, Ws, (Als, Wls)

  const int tid = threadIdx.x;
  const int w = tid >> 6;
  const int l = tid & 63;
  const int wm = w >> 1, wn = w & 1;
  const int m0 = blockIdx.y * 128;
  const int n0 = blockIdx.x * 128;

  const f16* gA  = Ah + (size_t)m0 * K;
  const f16* gW  = Wh + (size_t)n0 * K;
  const f16* gAl = (NSPLIT == 3) ? Al + (size_t)m0 * K : nullptr;
  const f16* gWl = (NSPLIT == 3) ? Wl + (size_t)n0 * K : nullptr;

  // fragment read offsets (unchanged; XOR matches staging swizzle)
  const int fbase = (l & 15) * 32 + (((l >> 4) ^ (l & 3)) * 8);
  const int fA = wm * 2048 + fbase;
  const int fW = wn * 2048 + fbase;

  // staging: slot s = w*128 + c*64 + l covers LDS[srow][schk], srow=s>>2,
  // schk=s&3; global chunk = schk ^ (srow&3)  =>  LDS[r][c]=G[r][c^(r&3)].
  const int s0   = w * 128 + l;
  const int dl0  = (w * 128) * 8;          // wave-uniform f16 offsets
  const int dl1  = (w * 128 + 64) * 8;

  f32x4 acc[4][4] = {};

  auto stage = [&](int k0, int bsel) {
    {
      const int s = s0;
      const int srow = s >> 2;
      const int koff = k0 + (((s & 3) ^ (srow & 3)) * 8);
      const size_t go = (size_t)srow * K + koff;
      gl16(gA + go, &smem[bsel][dl0]);
      gl16(gW + go, &smem[bsel][4096 + dl0]);
      if constexpr (NSPLIT == 3) {
        gl16(gAl + go, &smem[bsel][8192 + dl0]);
        gl16(gWl + go, &smem[bsel][12288 + dl0]);
      }
    }
    {
      const int s = s0 + 64;
      const int srow = s >> 2;
      const int koff = k0 + (((s & 3) ^ (srow & 3)) * 8);
      const size_t go = (size_t)srow * K + koff;
      gl16(gA + go, &smem[bsel][dl1]);
      gl16(gW + go, &smem[bsel][4096 + dl1]);
      if constexpr (NSPLIT == 3) {
        gl16(gAl + go, &smem[bsel][8192 + dl1]);
        gl16(gWl + go, &smem[bsel][12288 + dl1]);
      }
    }
  };

  stage(0, 0);
  __syncthreads();
  int buf = 0;

  for (int k0 = 0; k0 < K; k0 += 32) {
    if (k0 + 32 < K) stage(k0 + 32, buf ^ 1);   // async; in flight under MFMAs

    const f16* Ls = smem[buf];
    f16x8 ah[4], wh[4], al[4], wl[4];
#pragma unroll
    for (int i = 0; i < 4; ++i) ah[i] = *(const f16x8*)&Ls[fA + i * 512];
#pragma unroll
    for (int j = 0; j < 4; ++j) wh[j] = *(const f16x8*)&Ls[4096 + fW + j * 512];
    if constexpr (NSPLIT == 3) {
#pragma unroll
      for (int i = 0; i < 4; ++i) al[i] = *(const f16x8*)&Ls[8192 + fA + i * 512];
#pragma unroll
      for (int j = 0; j < 4; ++j) wl[j] = *(const f16x8*)&Ls[12288 + fW + j * 512];
    }

#pragma unroll
    for (int i = 0; i < 4; ++i)
#pragma unroll
      for (int j = 0; j < 4; ++j)
        acc[i][j] = __builtin_amdgcn_mfma_f32_16x16x32_f16(ah[i], wh[j], acc[i][j], 0, 0, 0);
    if constexpr (NSPLIT == 3) {
#pragma unroll
      for (int i = 0; i < 4; ++i)
#pragma unroll
        for (int j = 0; j < 4; ++j)
          acc[i][j] = __builtin_amdgcn_mfma_f32_16x16x32_f16(ah[i], wl[j], acc[i][j], 0, 0, 0);
#pragma unroll
      for (int i = 0; i < 4; ++i)
#pragma unroll
        for (int j = 0; j < 4; ++j)
          acc[i][j] = __builtin_amdgcn_mfma_f32_16x16x32_f16(al[i], wh[j], acc[i][j], 0, 0, 0);
    }
    __syncthreads();   // drains vmcnt (next buf ready) + all reads of buf done
    buf ^= 1;
  }

  const int rr = (l >> 4) * 4;
  const int cc = l & 15;
#pragma unroll
  for (int j = 0; j < 4; ++j) {
    const int n = n0 + wn * 64 + j * 16 + cc;
    const float bv = bias[n];
#pragma unroll
    for (int i = 0; i < 4; ++i) {
      const int m = m0 + wm * 64 + i * 16 + rr;
#pragma unroll
      for (int r = 0; r < 4; ++r) {
        const float val = acc[i][j][r] * inv + bv;
        if constexpr (OUT == 0) {
          C[(size_t)(m + r) * N + n] = val;
        } else {
          const float sv = val * oscale;
          const f16 hh = (f16)sv;
          const f16 ll = (f16)(sv - (float)hh);
          Ch[(size_t)(m + r) * N + n] = hh;
          Cl[(size_t)(m + r) * N + n] = ll;
        }
      }
    }
  }
}

// ---------------------------------------------------------------------------
// Canonical split-3 QK^T accumulation for one 32x32 tile. Same op order in
// main loop and slow-path recompute => bit-identical results.
// ---------------------------------------------------------------------------
__device__ __forceinline__ f32x16 qk_accum(const f16x8 ah[4], const f16x8 al[4],
                                           const f16x8 qh_[4], const f16x8 ql_[4]) {
  f32x16 ca = (f32x16){};
  f32x16 cb = (f32x16){};
  ca = MFMA32(ah[0], qh_[0], ca);  cb = MFMA32(ah[1], qh_[1], cb);
  ca = MFMA32(ah[2], qh_[2], ca);  cb = MFMA32(ah[3], qh_[3], cb);
  ca = MFMA32(al[0], qh_[0], ca);  cb = MFMA32(al[1], qh_[1], cb);
  ca = MFMA32(al[2], qh_[2], ca);  cb = MFMA32(al[3], qh_[3], cb);
  ca = MFMA32(ah[0], ql_[0], ca);  cb = MFMA32(ah[1], ql_[1], cb);
  ca = MFMA32(ah[2], ql_[2], ca);  cb = MFMA32(ah[3], ql_[3], cb);
  return ca + cb;
}

__device__ __forceinline__ f32x16 qk_tile_global(const f16* __restrict__ kgh,
                                                 const f16* __restrict__ kgl,
                                                 int tt, int q5, int hi5,
                                                 const f16x8 qh_[4], const f16x8 ql_[4]) {
  const f16* kh = kgh + (size_t)(tt * 32 + q5) * DE + hi5 * 8;
  const f16* kl = kgl + (size_t)(tt * 32 + q5) * DE + hi5 * 8;
  f16x8 ah[4], al[4];
#pragma unroll
  for (int s = 0; s < 4; ++s) {
    ah[s] = *(const f16x8*)(kh + s * 16);
    al[s] = *(const f16x8*)(kl + s * 16);
  }
  return qk_accum(ah, al, qh_, ql_);
}

// ---------------------------------------------------------------------------
// Fused sparse attention v11 (FROZEN from R11) — GEMM structure + per-TILE
// max tracking; snapshot-based position recovery; exact slow path.
// ---------------------------------------------------------------------------
__global__ __launch_bounds__(256, 3)
void attn_v11(const f16* __restrict__ qhb, const f16* __restrict__ qlb,
              const f16* __restrict__ khb, const f16* __restrict__ klb,
              const float* __restrict__ vb, f16* __restrict__ ob) {
  __shared__ f16 Ks[2][2][4096];     // [dbuf][hi/lo][64kv x 64d swizzled] 32KB
  __shared__ float4 stat[4][32];     // per wave/row: {wt|-1, pa, pb, cnt}
  __shared__ int   sidx[4][48];      // slow-path gather lists (per wave)
  __shared__ float sp[4][48];
  __shared__ int   scnt[4][2];

  const int phys = blockIdx.x;
  const int bid = (phys & 7) * 128 + (phys >> 3);   // 1024 blocks, bijective
  const int b  = bid >> 7;
  const int h  = (bid >> 4) & 7;
  const int qt = bid & 15;
  const int tid = threadIdx.x;
  const int w  = tid >> 6;
  const int l  = tid & 63;
  const int q5 = l & 31;
  const int hi5 = l >> 5;

  const float C2 = 1.44269504f / 4096.0f;

  const int qrow = qt * 128 + w * 32 + q5;
  const f16* qpb = qhb + (size_t)(b * SQB + qrow) * DE + h * DH + hi5 * 8;
  const f16* qpl = qlb + (size_t)(b * SQB + qrow) * DE + h * DH + hi5 * 8;
  f16x8 qh_[4], ql_[4];
#pragma unroll
  for (int s = 0; s < 4; ++s) {
    qh_[s] = *(const f16x8*)(qpb + s * 16);
    ql_[s] = *(const f16x8*)(qpl + s * 16);
  }

  const f16* kgh = khb + (size_t)(b * SKVB) * DE + h * DH;
  const f16* kgl = klb + (size_t)(b * SKVB) * DE + h * DH;

  const int skv0 = tid >> 3;
  const int sch  = tid & 7;
  const int d_off0 = skv0 * 64 + ((sch ^ (skv0 & 7)) * 8);
  const int d_off1 = (32 + skv0) * 64 + ((sch ^ (skv0 & 7)) * 8);

  {
    const f16* shp = kgh + (size_t)skv0 * DE + sch * 8;
    const f16* slp = kgl + (size_t)skv0 * DE + sch * 8;
    uint4 a0 = *(const uint4*)(shp);
    uint4 a1 = *(const uint4*)(shp + 32 * DE);
    uint4 b0 = *(const uint4*)(slp);
    uint4 b1 = *(const uint4*)(slp + 32 * DE);
    *(uint4*)&Ks[0][0][d_off0] = a0;
    *(uint4*)&Ks[0][0][d_off1] = a1;
    *(uint4*)&Ks[0][1][d_off0] = b0;
    *(uint4*)&Ks[0][1][d_off1] = b1;
  }
  __syncthreads();

  float m = -INFINITY, Z = 0.f, H = 0.f;
  int mt = 0;
  bool tie = false;
  f32x16 best = (f32x16){};

  for (int t = 0; t < 16; ++t) {
    const int cur = t & 1;
    const int nxt = cur ^ 1;
    uint4 La0, La1, Lb0, Lb1;
    const bool more = (t + 1 < 16);
    if (more) {
      const f16* shp = kgh + (size_t)((t + 1) * 64 + skv0) * DE + sch * 8;
      const f16* slp = kgl + (size_t)((t + 1) * 64 + skv0) * DE + sch * 8;
      La0 = *(const uint4*)(shp);
      La1 = *(const uint4*)(shp + 32 * DE);
      Lb0 = *(const uint4*)(slp);
      Lb1 = *(const uint4*)(slp + 32 * DE);
    }
#pragma unroll
    for (int u = 0; u < 2; ++u) {
      const int kvl = u * 32 + q5;
      const int rowoff = kvl * 64;
      f16x8 ah[4], al[4];
#pragma unroll
      for (int s = 0; s < 4; ++s) {
        const int idx = rowoff + (((s * 2 + hi5) ^ (q5 & 7)) * 8);
        ah[s] = *(const f16x8*)&Ks[cur][0][idx];
        al[s] = *(const f16x8*)&Ks[cur][1][idx];
      }
      const f32x16 sv = qk_accum(ah, al, qh_, ql_);
      float t0 = fmaxf(fmaxf(sv[0], sv[1]), fmaxf(sv[2], sv[3]));
      float t1 = fmaxf(fmaxf(sv[4], sv[5]), fmaxf(sv[6], sv[7]));
      float t2 = fmaxf(fmaxf(sv[8], sv[9]), fmaxf(sv[10], sv[11]));
      float t3 = fmaxf(fmaxf(sv[12], sv[13]), fmaxf(sv[14], sv[15]));
      const float tmax = fmaxf(fmaxf(t0, t1), fmaxf(t2, t3));
#pragma unroll
      for (int r = 0; r < 16; ++r) {
        const float s = sv[r];
        const float e = __builtin_amdgcn_exp2f(s * C2);
        Z += e;
        H = fmaf(e, s, H);
      }
      const bool upd = (tmax > m);
      tie = upd ? false : (tie || (tmax == m));
      if (upd) { m = tmax; mt = t * 2 + u; }
#pragma unroll
      for (int r = 0; r < 16; ++r) best[r] = upd ? sv[r] : best[r];
    }
    if (more) {
      *(uint4*)&Ks[nxt][0][d_off0] = La0;
      *(uint4*)&Ks[nxt][0][d_off1] = La1;
      *(uint4*)&Ks[nxt][1][d_off0] = Lb0;
      *(uint4*)&Ks[nxt][1][d_off1] = Lb1;
    }
    __syncthreads();
  }

  const float mo = __shfl_xor(m, 32);
  const int tieo = __shfl_xor(tie ? 1 : 0, 32);
  Z += __shfl_xor(Z, 32);
  H += __shfl_xor(H, 32);
  const float mc = fmaxf(m, mo);
  const bool tiec = (m > mo) ? tie : ((mo > m) ? (tieo != 0) : (tie || tieo != 0));

  int c = 0, p1 = -1, p2 = -1;
#pragma unroll
  for (int r = 0; r < 16; ++r) {
    if (best[r] == mc) {
      const int pos = mt * 32 + (r & 3) + 8 * (r >> 2) + 4 * hi5;
      p2 = (c == 1) ? pos : p2;
      p1 = (c == 0) ? pos : p1;
      ++c;
    }
  }
  const int co  = __shfl_xor(c, 32);
  const int p1o = __shfl_xor(p1, 32);
  const int p2o = __shfl_xor(p2, 32);
  const int ct = c + co;
  const int pa = (c > 0) ? p1 : p1o;
  const int pb = (c >= 2) ? p2 : ((c == 1) ? ((co > 0) ? p1o : -1)
                                           : ((co >= 2) ? p2o : -1));

  const float E = __logf(Z) - (H * (1.0f / 4096.0f)) / Z;
  int tk = (int)(32.0f * (1.0f - E));
  tk = tk < 1 ? 1 : (tk > 32 ? 32 : tk);
  const bool slowRow = (tk > 1) || tiec || (ct > 2);
  const float zeps = 1e-8f * Z * __builtin_amdgcn_exp2f(-mc * C2);
  const float wt = 1.0f / ((float)ct + zeps);

  if (hi5 == 0)
    stat[w][q5] = make_float4(slowRow ? -1.0f : wt,
                              __int_as_float(pa),
                              __int_as_float(ct == 2 ? pb : -1),
                              (float)ct);

  {
    const size_t obase = (size_t)(b * SQB + qt * 128 + w * 32) * DE + h * DH + l;
    const float* vB = vb + (size_t)(b * SKVB) * DE + h * DH + l;
    for (int r = 0; r < 32; ++r) {
      const float4 st = stat[w][r];
      if (st.x >= 0.f) {
        const int ppa = __float_as_int(st.y);
        const int ppb = __float_as_int(st.z);
        float acc = vB[(size_t)ppa * DE];
        if (ppb >= 0) acc += vB[(size_t)ppb * DE];
        ob[obase + (size_t)r * DE] = (f16)(acc * st.x);
      }
    }
  }

  {
    unsigned long long sb = __ballot(slowRow && hi5 == 0);
    while (sb != 0ull) {
      const int rr = (int)__builtin_ctzll(sb);
      sb &= sb - 1;
      const float mr = __shfl(mc, rr);
      const int tkr  = __shfl(tk, rr);
      const float Zr = __shfl(Z, rr);
      float thr = mr;
      float rem = (float)tkr;
      float cand = mr;
      int guard = 0;
      bool done = false;
      while (!done && guard < 40) {
        ++guard;
        float cf = 0.f, nmx = -INFINITY;
        for (int tt = 0; tt < 32; ++tt) {
          const f32x16 sv = qk_tile_global(kgh, kgl, tt, q5, hi5, qh_, ql_);
          if (q5 == rr) {
#pragma unroll
            for (int r = 0; r < 16; ++r) {
              cf += (sv[r] == cand) ? 1.f : 0.f;
              nmx = (sv[r] < cand) ? fmaxf(nmx, sv[r]) : nmx;
            }
          }
        }
        cf += __shfl_xor(cf, 32);
        nmx = fmaxf(nmx, __shfl_xor(nmx, 32));
        const float cfr = __shfl(cf, rr);
        const float nmr = __shfl(nmx, rr);
        if (cfr >= rem) { thr = cand; done = true; }
        else { rem -= cfr; cand = nmr; }
      }
      int myc = 0;
      for (int tt = 0; tt < 32; ++tt) {
        const f32x16 sv = qk_tile_global(kgh, kgl, tt, q5, hi5, qh_, ql_);
        if (q5 == rr) {
#pragma unroll
          for (int r = 0; r < 16; ++r) {
            if (sv[r] >= thr && myc < 24) {
              sidx[w][hi5 * 24 + myc] = tt * 32 + (r & 3) + 8 * (r >> 2) + 4 * hi5;
              sp[w][hi5 * 24 + myc] = __builtin_amdgcn_exp2f((sv[r] - mr) * C2);
              ++myc;
            }
          }
        }
      }
      if (q5 == rr) scnt[w][hi5] = myc;
      int c0 = scnt[w][0]; c0 = c0 > 24 ? 24 : c0;
      int c1 = scnt[w][1]; c1 = c1 > 24 ? 24 : c1;
      float acc = 0.f, ps = 0.f;
      const float* vB = vb + (size_t)(b * SKVB) * DE + h * DH + l;
      for (int e = 0; e < c0; ++e) {
        const int kv = sidx[w][e]; const float p = sp[w][e];
        ps += p; acc = fmaf(p, vB[(size_t)kv * DE], acc);
      }
      for (int e = 0; e < c1; ++e) {
        const int kv = sidx[w][24 + e]; const float p = sp[w][24 + e];
        ps += p; acc = fmaf(p, vB[(size_t)kv * DE], acc);
      }
      const float zepsr = 1e-8f * Zr * __builtin_amdgcn_exp2f(-mr * C2);
      const float o = acc / (ps + zepsr);
      ob[(size_t)(b * SQB + qt * 128 + w * 32 + rr) * DE + h * DH + l] = (f16)o;
    }
  }
}

// ---------------------------------------------------------------------------
extern "C" void kernel_launch(void* const* d_in, const int* in_sizes, int n_in,
                              void* d_out, int out_size, void* d_ws, size_t ws_size,
                              hipStream_t stream) {
  const float* x  = (const float*)d_in[0];
  const float* y  = (const float*)d_in[1];
  const float* wq = (const float*)d_in[2];
  const float* bq = (const float*)d_in[3];
  const float* wk = (const float*)d_in[4];
  const float* bk = (const float*)d_in[5];
  const float* wv = (const float*)d_in[6];
  const float* bv = (const float*)d_in[7];
  const float* wo = (const float*)d_in[8];
  const float* bo = (const float*)d_in[9];
  float* out = (float*)d_out;

  char* ws = (char*)d_ws;
  const size_t MiB = 1048576;

  f16* xh  = (f16*)(ws);                       // 16 MiB
  f16* xl  = (f16*)(ws + 16 * MiB);            // 16
  f16* yh  = (f16*)(ws + 32 * MiB);            // 12
  f16* yl  = (f16*)(ws + 44 * MiB);            // 12
  f16* qh  = (f16*)(ws + 56 * MiB);            // 16
  f16* ql  = (f16*)(ws + 72 * MiB);            // 16
  f16* kh  = (f16*)(ws + 88 * MiB);            // 8
  f16* kl  = (f16*)(ws + 96 * MiB);            // 8
  float* v = (float*)(ws + 104 * MiB);         // 16 (f32)
  f16* ao  = (f16*)(ws + 120 * MiB);           // 16
  f16* wqh = (f16*)(ws + 136 * MiB);
  f16* wql = (f16*)(ws + 136 * MiB + 524288);
  f16* wkh = (f16*)(ws + 137 * MiB);
  f16* wkl = (f16*)(ws + 137 * MiB + 786432);
  f16* wvh = (f16*)(ws + 138 * MiB + 524288);
  f16* wvl = (f16*)(ws + 139 * MiB + 262144);
  f16* woh = (f16*)(ws + 140 * MiB);
  f16* wol = (f16*)(ws + 140 * MiB + 524288);

  dim3 blk(256);
  const float WS = 2048.0f, IWS = 1.0f / 2048.0f;

  // x + y activation splits (one launch)
  split2<<<dim3(14336), blk, 0, stream>>>(x, xh, xl, 2097152,
                                          y, yh, yl, 1572864);
  // all weight splits (one launch)
  split4<<<dim3(1280), blk, 0, stream>>>(wq, wqh, wql, 65536, WS,
                                         wk, wkh, wkl, 98304, WS,
                                         wv, wvh, wvl, 98304, 1.0f,
                                         wo, woh, wol, 65536, 1.0f);

  // Q-proj -> split pair scaled x8  (q_true * 0.125 * 64)
  gemm_f16<3, 1><<<dim3(4, 128), blk, 0, stream>>>(xh, xl, wqh, wql, bq,
      nullptr, qh, ql, 16384, 512, 512, IWS, 8.0f);
  // K-proj -> split pair scaled x64
  gemm_f16<3, 1><<<dim3(4, 64), blk, 0, stream>>>(yh, yl, wkh, wkl, bk,
      nullptr, kh, kl, 8192, 512, 768, IWS, 64.0f);
  // V-proj -> f32
  gemm_f16<1, 0><<<dim3(4, 64), blk, 0, stream>>>(yh, nullptr, wvh, nullptr, bv,
      v, nullptr, nullptr, 8192, 512, 768, 1.0f, 1.0f);

  attn_v11<<<dim3(1024), blk, 0, stream>>>(qh, ql, kh, kl, v, ao);

  // O-proj
  gemm_f16<1, 0><<<dim3(4, 128), blk, 0, stream>>>(ao, nullptr, woh, nullptr, bo,
      out, nullptr, nullptr, 16384, 512, 512, 1.0f, 1.0f);
}